// Round 7
// baseline (208.215 us; speedup 1.0000x reference)
//
#include <hip/hip_runtime.h>
#include <math.h>
#include <float.h>

#define BB 256
#define NN 400
#define DD 512
#define KK 20
#define NCH 4     // d-chunks per batch
#define CHD 128   // chunk width

__device__ __forceinline__ float dot8(float4 a0, float4 a1, float4 b0, float4 b1) {
    return a0.x*b0.x + a0.y*b0.y + a0.z*b0.z + a0.w*b0.w
         + a1.x*b1.x + a1.y*b1.y + a1.z*b1.z + a1.w*b1.w;
}

// One block per (batch, d-chunk). 256 threads = 4 waves. 1024 blocks = 4/CU.
__global__ __launch_bounds__(256, 4) void fused_all_kernel(
    const float* __restrict__ embs,   // [B, N, D]
    const float* __restrict__ h_t,    // [B, D]
    const float* __restrict__ W,      // [D, D]
    const float* __restrict__ bmap,   // [D]
    float* __restrict__ out0,         // [B, K, K]
    float* __restrict__ out1,         // [B]
    float* __restrict__ out2,         // [B, D] scorer
    float* __restrict__ out3,         // [B] entropy
    float* __restrict__ out4,         // [B, K] indices as float
    float* __restrict__ ws_partial,   // [B*NCH*NN]
    float* __restrict__ ws_ss,        // [B*NCH]
    int*   __restrict__ ws_cnt)       // [B] (zeroed per launch)
{
    const int blk = blockIdx.x;
    const int b = blk >> 2, c = blk & 3;
    const int t = threadIdx.x;
    const int wave = t >> 6, lane = t & 63;

    __shared__ float sc_lds[CHD];
    __shared__ float red[4], red2[4];
    __shared__ float sh_s[NN];
    __shared__ float mZ[3];           // inv_norm, m, logZ
    __shared__ int   sh_topk[KK];
    __shared__ float sh_th[KK];
    __shared__ int   sh_flag;

    // ---- Phase 1: scorer chunk rows [128c, 128c+128); wave w -> 16 row-pairs ----
    const float4* hp = (const float4*)(h_t + (size_t)b * DD);
    const float4 h0 = hp[lane], h1 = hp[lane + 64];
    {
        const int dbase = c * CHD + wave * 32;
        #pragma unroll 4
        for (int p = 0; p < 16; ++p) {
            const int d0 = dbase + 2 * p, d1 = d0 + 1;
            const float4* wp0 = (const float4*)(W + (size_t)d0 * DD);
            const float4* wp1 = (const float4*)(W + (size_t)d1 * DD);
            float4 a0 = wp0[lane], a1 = wp0[lane + 64];
            float4 b0 = wp1[lane], b1 = wp1[lane + 64];
            float p0 = dot8(a0, a1, h0, h1);
            float p1 = dot8(b0, b1, h0, h1);
            #pragma unroll
            for (int off = 32; off; off >>= 1) {
                p0 += __shfl_xor(p0, off, 64);
                p1 += __shfl_xor(p1, off, 64);
            }
            if (lane == 0) {
                sc_lds[d0 - c * CHD] = tanhf(p0 + bmap[d0]);
                sc_lds[d1 - c * CHD] = tanhf(p1 + bmap[d1]);
            }
        }
    }
    __syncthreads();

    // ss partial + scorer output (threads 0..127 = waves 0,1)
    if (t < CHD) {
        float v = sc_lds[t];
        out2[(size_t)b * DD + c * CHD + t] = v;
        float ss = v * v;
        #pragma unroll
        for (int off = 32; off; off >>= 1) ss += __shfl_xor(ss, off, 64);
        if (lane == 0) red[wave] = ss;
    }
    __syncthreads();
    if (t == 0) ws_ss[b * NCH + c] = red[0] + red[1];

    // ---- Phase 2: stream embs chunk; wave w -> rows [100w, 100w+100) ----
    {
        const int half = lane >> 5;       // which of the 2 rows this half handles
        const int col  = lane & 31;       // float4 index within the 512B chunk
        const float4 sc4 = ((const float4*)sc_lds)[col];
        const float4* base4 = (const float4*)(embs
            + ((size_t)b * NN + wave * 100 + half) * DD + c * CHD);
        float* pout = ws_partial + ((size_t)(b * NCH + c)) * NN + wave * 100;

        for (int g = 0; g < 10; ++g) {
            float4 A[5];
            #pragma unroll
            for (int r = 0; r < 5; ++r)
                A[r] = base4[col + (size_t)(5 * g + r) * 256];  // 2 rows / inst
            float s[5];
            #pragma unroll
            for (int r = 0; r < 5; ++r)
                s[r] = A[r].x * sc4.x + A[r].y * sc4.y + A[r].z * sc4.z + A[r].w * sc4.w;
            #pragma unroll
            for (int off = 1; off < 32; off <<= 1) {
                #pragma unroll
                for (int r = 0; r < 5; ++r) s[r] += __shfl_xor(s[r], off, 64);
            }
            if (col == 0) {
                #pragma unroll
                for (int r = 0; r < 5; ++r) pout[2 * (5 * g + r) + half] = s[r];
            }
        }
    }

    // ---- last-finisher election ----
    __threadfence();
    __syncthreads();
    if (t == 0) {
        int old = atomicAdd(ws_cnt + b, 1);
        sh_flag = (old == NCH - 1) ? 1 : 0;
    }
    __syncthreads();
    if (!sh_flag) return;
    __threadfence();  // acquire: see other blocks' partials/ss

    // ---- Finalize (4 waves) ----
    const float* pb = ws_partial + (size_t)b * NCH * NN;
    float r0 = 0.f, r1 = 0.f;
    {
        // n = t and n = t+256 (t<144)
        r0 = pb[t] + pb[NN + t] + pb[2 * NN + t] + pb[3 * NN + t];
        if (t < NN - 256) {
            int n = t + 256;
            r1 = pb[n] + pb[NN + n] + pb[2 * NN + n] + pb[3 * NN + n];
        }
    }
    if (t == 0) {
        float tot = ws_ss[b * NCH] + ws_ss[b * NCH + 1]
                  + ws_ss[b * NCH + 2] + ws_ss[b * NCH + 3];
        mZ[0] = 1.0f / sqrtf(tot);
    }
    __syncthreads();
    const float inv = mZ[0];
    const float x0 = r0 * inv;
    const float x1 = (t < NN - 256) ? r1 * inv : -FLT_MAX;
    sh_s[t] = x0;
    if (t < NN - 256) sh_s[t + 256] = x1;

    // block max
    {
        float m = fmaxf(x0, x1);
        #pragma unroll
        for (int off = 32; off; off >>= 1) m = fmaxf(m, __shfl_xor(m, off, 64));
        if (lane == 0) red[wave] = m;
    }
    __syncthreads();
    if (t == 0) mZ[1] = fmaxf(fmaxf(red[0], red[1]), fmaxf(red[2], red[3]));
    __syncthreads();
    const float m = mZ[1];

    // Z and entropy sums
    {
        float d0 = x0 - m;
        float e = expf(d0), wv = e * d0;
        if (t < NN - 256) {
            float d1 = x1 - m;
            float e1 = expf(d1);
            e += e1; wv += e1 * d1;
        }
        #pragma unroll
        for (int off = 32; off; off >>= 1) {
            e  += __shfl_xor(e, off, 64);
            wv += __shfl_xor(wv, off, 64);
        }
        if (lane == 0) { red[wave] = e; red2[wave] = wv; }
    }
    __syncthreads();
    if (t == 0) {
        float Z = red[0] + red[1] + red[2] + red[3];
        float Ws = red2[0] + red2[1] + red2[2] + red2[3];
        float logZ = logf(Z);
        mZ[2] = logZ;
        out3[b] = logZ - Ws / Z;
    }
    __syncthreads();
    const float logZ = mZ[2];

    // top-K on wave 0, fully in-register (verified r3 logic; sh_s pre-scaled)
    if (wave == 0) {
        float v0 = sh_s[lane      ];
        float v1 = sh_s[lane +  64];
        float v2 = sh_s[lane + 128];
        float v3 = sh_s[lane + 192];
        float v4 = sh_s[lane + 256];
        float v5 = sh_s[lane + 320];
        float v6 = (lane + 384 < NN) ? sh_s[lane + 384] : -FLT_MAX;
        float acc = 0.f;
        for (int k = 0; k < KK; ++k) {
            float bv = v0; int bi = lane;
            if (v1 > bv) { bv = v1; bi = lane + 64; }
            if (v2 > bv) { bv = v2; bi = lane + 128; }
            if (v3 > bv) { bv = v3; bi = lane + 192; }
            if (v4 > bv) { bv = v4; bi = lane + 256; }
            if (v5 > bv) { bv = v5; bi = lane + 320; }
            if (v6 > bv) { bv = v6; bi = lane + 384; }
            #pragma unroll
            for (int off = 32; off; off >>= 1) {
                float ov = __shfl_xor(bv, off, 64);
                int   oi = __shfl_xor(bi, off, 64);
                if (ov > bv || (ov == bv && oi < bi)) { bv = ov; bi = oi; }
            }
            if (lane == 0) {
                sh_topk[k] = bi;
                sh_th[k] = tanhf(bv);
                out4[(size_t)b * KK + k] = (float)bi;
                acc += bv - m - logZ;
            }
            v0 = (bi == lane      ) ? -FLT_MAX : v0;
            v1 = (bi == lane +  64) ? -FLT_MAX : v1;
            v2 = (bi == lane + 128) ? -FLT_MAX : v2;
            v3 = (bi == lane + 192) ? -FLT_MAX : v3;
            v4 = (bi == lane + 256) ? -FLT_MAX : v4;
            v5 = (bi == lane + 320) ? -FLT_MAX : v5;
            v6 = (bi == lane + 384) ? -FLT_MAX : v6;
        }
        if (lane == 0) out1[b] = acc / (float)KK;
    }
    __syncthreads();

    // out0[b, j, k] = embs[b, topk[k], j] * th[k]; two passes cover 400 elems
    if (t < NN) {
        int k = t / KK;
        int j = t - k * KK;
        float val = embs[((size_t)b * NN + sh_topk[k]) * DD + j] * sh_th[k];
        out0[(size_t)b * (KK * KK) + j * KK + k] = val;
    }
}

extern "C" void kernel_launch(void* const* d_in, const int* in_sizes, int n_in,
                              void* d_out, int out_size, void* d_ws, size_t ws_size,
                              hipStream_t stream) {
    const float* node_embs = (const float*)d_in[0];
    // d_in[1] = mask, unused
    const float* h_t   = (const float*)d_in[2];
    const float* W_map = (const float*)d_in[3];
    const float* b_map = (const float*)d_in[4];
    (void)in_sizes; (void)n_in; (void)out_size; (void)ws_size;

    float* ob = (float*)d_out;
    float* out0 = ob;                       // [B,K,K] -> 102400
    float* out1 = ob + 102400;              // [B]     -> 256
    float* out2 = ob + 102656;              // [B,D]   -> 131072
    float* out3 = ob + 233728;              // [B]     -> 256
    float* out4 = ob + 233984;              // [B,K]   -> 5120

    int*   ws_cnt     = (int*)d_ws;                    // 256 ints
    float* ws_ss      = (float*)d_ws + 256;            // 1024 floats
    float* ws_partial = (float*)d_ws + 256 + 1024;     // 409600 floats

    // re-zero the election counters every launch (captured in the graph)
    hipMemsetAsync(ws_cnt, 0, BB * sizeof(int), stream);

    fused_all_kernel<<<BB * NCH, 256, 0, stream>>>(
        node_embs, h_t, W_map, b_map,
        out0, out1, out2, out3, out4,
        ws_partial, ws_ss, ws_cnt);
}

// Round 8
// 74.159 us; speedup vs baseline: 2.8077x; 2.8077x over previous
//
#include <hip/hip_runtime.h>
#include <math.h>
#include <float.h>

#define BB 256
#define NN 400
#define DD 512
#define KK 20
#define SROWS 64   // embs rows staged in LDS during phase A

__device__ __forceinline__ float dot8(float4 a0, float4 a1, float4 b0, float4 b1) {
    return a0.x*b0.x + a0.y*b0.y + a0.z*b0.z + a0.w*b0.w
         + a1.x*b1.x + a1.y*b1.y + a1.z*b1.z + a1.w*b1.w;
}

// async global->LDS, 16B per lane; LDS dest = uniform base + lane*16 (HW rule)
__device__ __forceinline__ void gload_lds16(const float* g, float* l) {
    __builtin_amdgcn_global_load_lds(
        (const __attribute__((address_space(1))) void*)g,
        (__attribute__((address_space(3))) void*)l, 16, 0, 0);
}

// One block per batch, 1024 threads = 16 waves, 1 block/CU (128KB dynamic LDS).
__global__ __launch_bounds__(1024, 4) void fused_topk_kernel(
    const float* __restrict__ embs,    // [B, N, D]
    const float* __restrict__ h_t,     // [B, D]
    const float* __restrict__ W,       // [D, D]
    const float* __restrict__ bmap,    // [D]
    float* __restrict__ out0,          // [B, K, K]
    float* __restrict__ out1,          // [B]
    float* __restrict__ out2,          // [B, D] scorer
    float* __restrict__ out3,          // [B] entropy
    float* __restrict__ out4)          // [B, K] indices as float
{
    const int b = blockIdx.x;
    const int t = threadIdx.x;
    const int wave = t >> 6, lane = t & 63;

    extern __shared__ float sh_rows[];            // [SROWS*DD] = 128 KB
    __shared__ float sh_sc[DD];
    __shared__ float sh_s[NN];
    __shared__ float redf[16], redf2[16], redq[8];
    __shared__ float mZ[3];                       // inv_norm, m, logZ
    __shared__ int   sh_topk[KK];
    __shared__ float sh_th[KK];

    // ---- Phase A, waves 0-7: scorer rows [64w, 64w+64) (32 pairs) ----
    if (wave < 8) {
        const float4* hp = (const float4*)(h_t + (size_t)b * DD);
        const float4 h0 = hp[lane], h1 = hp[lane + 64];
        const int dbase = wave * 64;
        #pragma unroll 4
        for (int p = 0; p < 32; ++p) {
            const int d0 = dbase + 2 * p, d1 = d0 + 1;
            const float4* wp0 = (const float4*)(W + (size_t)d0 * DD);
            const float4* wp1 = (const float4*)(W + (size_t)d1 * DD);
            float4 a0 = wp0[lane], a1 = wp0[lane + 64];
            float4 c0 = wp1[lane], c1 = wp1[lane + 64];
            float s0 = dot8(a0, a1, h0, h1);
            float s1 = dot8(c0, c1, h0, h1);
            #pragma unroll
            for (int off = 32; off; off >>= 1) {
                s0 += __shfl_xor(s0, off, 64);
                s1 += __shfl_xor(s1, off, 64);
            }
            if (lane == 0) {
                sh_sc[d0] = tanhf(s0 + bmap[d0]);
                sh_sc[d1] = tanhf(s1 + bmap[d1]);
            }
        }
    } else {
        // ---- Phase A, waves 8-15: stage embs rows [8ws, 8ws+8) into LDS ----
        const int ws = wave - 8;
        const float* gbase = embs + ((size_t)b * NN + ws * 8) * DD;
        #pragma unroll
        for (int r = 0; r < 8; ++r) {
            const float* grow = gbase + (size_t)r * DD + lane * 4;
            float* lrow = sh_rows + (size_t)(ws * 8 + r) * DD;
            gload_lds16(grow,            lrow);
            gload_lds16(grow + 256,      lrow + 256);
        }
        asm volatile("s_waitcnt vmcnt(0)" ::: "memory");
    }
    __syncthreads();

    // scorer out + sum-of-squares partials (waves 0..7 cover 512 elems)
    if (t < DD) {
        float v = sh_sc[t];
        out2[(size_t)b * DD + t] = v;
        float ss = v * v;
        #pragma unroll
        for (int off = 32; off; off >>= 1) ss += __shfl_xor(ss, off, 64);
        if (lane == 0) redq[wave] = ss;
    }

    const float4 g0 = ((const float4*)sh_sc)[lane];
    const float4 g1 = ((const float4*)sh_sc)[lane + 64];

    // ---- stream phase: wave w -> rows [25w, 25w+25); rows<64 from LDS ----
    {
        const int n0 = wave * 25;
        const float* base = embs + ((size_t)b * NN + n0) * DD;
        for (int g = 0; g < 5; ++g) {
            float4 A0[5], A1[5];
            #pragma unroll
            for (int r = 0; r < 5; ++r) {
                const int row = n0 + g * 5 + r;
                if (row < SROWS) {
                    const float4* lp = (const float4*)(sh_rows + (size_t)row * DD);
                    A0[r] = lp[lane]; A1[r] = lp[lane + 64];
                } else {
                    const float4* p = (const float4*)(base + (size_t)(g * 5 + r) * DD);
                    A0[r] = p[lane]; A1[r] = p[lane + 64];
                }
            }
            float s[5];
            #pragma unroll
            for (int r = 0; r < 5; ++r) s[r] = dot8(A0[r], A1[r], g0, g1);
            #pragma unroll
            for (int off = 32; off; off >>= 1) {
                #pragma unroll
                for (int r = 0; r < 5; ++r) s[r] += __shfl_xor(s[r], off, 64);
            }
            if (lane == 0) {
                float* o = sh_s + n0 + g * 5;
                #pragma unroll
                for (int r = 0; r < 5; ++r) o[r] = s[r];
            }
        }
    }
    __syncthreads();

    if (t == 0) {
        float tot = 0.f;
        #pragma unroll
        for (int i = 0; i < 8; ++i) tot += redq[i];
        mZ[0] = 1.0f / sqrtf(tot);
    }
    __syncthreads();
    const float inv = mZ[0];

    // ---- block max of scaled scores ----
    const float x = (t < NN) ? sh_s[t] * inv : -FLT_MAX;
    {
        float m = x;
        #pragma unroll
        for (int off = 32; off; off >>= 1) m = fmaxf(m, __shfl_xor(m, off, 64));
        if (lane == 0) redf[wave] = m;
    }
    __syncthreads();
    if (t == 0) {
        float m = redf[0];
        #pragma unroll
        for (int i = 1; i < 16; ++i) m = fmaxf(m, redf[i]);
        mZ[1] = m;
    }
    __syncthreads();
    const float m = mZ[1];

    // ---- Z and entropy sums ----
    {
        float e = 0.f, wv = 0.f;
        if (t < NN) {
            float d = x - m;
            e = expf(d);
            wv = e * d;
        }
        #pragma unroll
        for (int off = 32; off; off >>= 1) {
            e  += __shfl_xor(e, off, 64);
            wv += __shfl_xor(wv, off, 64);
        }
        if (lane == 0) { redf[wave] = e; redf2[wave] = wv; }
    }
    __syncthreads();
    if (t == 0) {
        float Z = 0.f, Ws = 0.f;
        #pragma unroll
        for (int i = 0; i < 16; ++i) { Z += redf[i]; Ws += redf2[i]; }
        float logZ = logf(Z);
        mZ[2] = logZ;
        out3[b] = logZ - Ws / Z;
    }
    __syncthreads();
    const float logZ = mZ[2];

    // ---- top-K on wave 0, fully in-register (r3-verified) ----
    if (wave == 0) {
        float v0 = sh_s[lane      ] * inv;
        float v1 = sh_s[lane +  64] * inv;
        float v2 = sh_s[lane + 128] * inv;
        float v3 = sh_s[lane + 192] * inv;
        float v4 = sh_s[lane + 256] * inv;
        float v5 = sh_s[lane + 320] * inv;
        float v6 = (lane + 384 < NN) ? sh_s[lane + 384] * inv : -FLT_MAX;
        float acc = 0.f;
        for (int k = 0; k < KK; ++k) {
            float bv = v0; int bi = lane;
            if (v1 > bv) { bv = v1; bi = lane + 64; }
            if (v2 > bv) { bv = v2; bi = lane + 128; }
            if (v3 > bv) { bv = v3; bi = lane + 192; }
            if (v4 > bv) { bv = v4; bi = lane + 256; }
            if (v5 > bv) { bv = v5; bi = lane + 320; }
            if (v6 > bv) { bv = v6; bi = lane + 384; }
            #pragma unroll
            for (int off = 32; off; off >>= 1) {
                float ov = __shfl_xor(bv, off, 64);
                int   oi = __shfl_xor(bi, off, 64);
                if (ov > bv || (ov == bv && oi < bi)) { bv = ov; bi = oi; }
            }
            if (lane == 0) {
                sh_topk[k] = bi;
                sh_th[k] = tanhf(bv);
                out4[(size_t)b * KK + k] = (float)bi;
                acc += bv - m - logZ;
            }
            v0 = (bi == lane      ) ? -FLT_MAX : v0;
            v1 = (bi == lane +  64) ? -FLT_MAX : v1;
            v2 = (bi == lane + 128) ? -FLT_MAX : v2;
            v3 = (bi == lane + 192) ? -FLT_MAX : v3;
            v4 = (bi == lane + 256) ? -FLT_MAX : v4;
            v5 = (bi == lane + 320) ? -FLT_MAX : v5;
            v6 = (bi == lane + 384) ? -FLT_MAX : v6;
        }
        if (lane == 0) out1[b] = acc / (float)KK;
    }
    __syncthreads();

    // ---- out0[b, j, k] = embs[b, topk[k], j] * th[k] ----
    if (t < NN) {
        int k = t / KK;
        int j = t - k * KK;
        int row = sh_topk[k];
        float val = (row < SROWS ? sh_rows[(size_t)row * DD + j]
                                 : embs[((size_t)b * NN + row) * DD + j]) * sh_th[k];
        out0[(size_t)b * (KK * KK) + j * KK + k] = val;
    }
}

extern "C" void kernel_launch(void* const* d_in, const int* in_sizes, int n_in,
                              void* d_out, int out_size, void* d_ws, size_t ws_size,
                              hipStream_t stream) {
    const float* node_embs = (const float*)d_in[0];
    // d_in[1] = mask, unused
    const float* h_t   = (const float*)d_in[2];
    const float* W_map = (const float*)d_in[3];
    const float* b_map = (const float*)d_in[4];
    (void)in_sizes; (void)n_in; (void)out_size; (void)d_ws; (void)ws_size;

    float* ob = (float*)d_out;
    float* out0 = ob;                       // [B,K,K] -> 102400
    float* out1 = ob + 102400;              // [B]     -> 256
    float* out2 = ob + 102656;              // [B,D]   -> 131072
    float* out3 = ob + 233728;              // [B]     -> 256
    float* out4 = ob + 233984;              // [B,K]   -> 5120

    const size_t dyn_lds = (size_t)SROWS * DD * sizeof(float);  // 128 KB
    fused_topk_kernel<<<BB, 1024, dyn_lds, stream>>>(
        node_embs, h_t, W_map, b_map, out0, out1, out2, out3, out4);
}

// Round 9
// 67.668 us; speedup vs baseline: 3.0770x; 1.0959x over previous
//
#include <hip/hip_runtime.h>
#include <math.h>
#include <float.h>

#define BB 256
#define NN 400
#define DD 512
#define KK 20

// One block per batch, 1024 threads = 16 waves.
// Row-dot scheme: 8 lanes per row ("octet"); lane = (rr = lane>>3, q = lane&7).
// Lane reads float4s at row*512 + (q+8k)*4, k=0..15 (immediate offsets),
// accumulates privately; 3 shfl_xor reduce per 8 rows. No long shuffle chains.
__global__ __launch_bounds__(1024, 4) void fused_topk_kernel(
    const float* __restrict__ embs,    // [B, N, D]
    const float* __restrict__ h_t,     // [B, D]
    const float* __restrict__ W,       // [D, D]
    const float* __restrict__ bmap,    // [D]
    float* __restrict__ out0,          // [B, K, K]
    float* __restrict__ out1,          // [B]
    float* __restrict__ out2,          // [B, D] scorer
    float* __restrict__ out3,          // [B] entropy
    float* __restrict__ out4)          // [B, K] indices as float
{
    const int b = blockIdx.x;
    const int t = threadIdx.x;
    const int wave = t >> 6, lane = t & 63;
    const int q  = lane & 7;
    const int rr = lane >> 3;

    __shared__ float sh_sc[DD];
    __shared__ float sh_s[NN];
    __shared__ float redf[16], redf2[16], redq[8];
    __shared__ float mZ[3];            // inv_norm, m, logZ
    __shared__ int   sh_topk[KK];
    __shared__ float sh_th[KK];

    // ================= Phase A: raw scorer dots (W rows) =================
    {
        const float4* hb = (const float4*)(h_t + (size_t)b * DD);
        float4 S[16];
        #pragma unroll
        for (int k = 0; k < 16; ++k) S[k] = hb[q + 8 * k];

        #pragma unroll
        for (int j = 0; j < 4; ++j) {
            const int row = (j * 16 + wave) * 8 + rr;     // W row (d), 0..511
            const float4* src = (const float4*)(W + (size_t)row * DD) + q;
            float a0 = 0.f, a1 = 0.f, a2 = 0.f, a3 = 0.f;
            #pragma unroll
            for (int k = 0; k < 16; ++k) {
                float4 e = src[8 * k];
                a0 += e.x * S[k].x;
                a1 += e.y * S[k].y;
                a2 += e.z * S[k].z;
                a3 += e.w * S[k].w;
            }
            float acc = (a0 + a1) + (a2 + a3);
            acc += __shfl_xor(acc, 1, 64);
            acc += __shfl_xor(acc, 2, 64);
            acc += __shfl_xor(acc, 4, 64);
            if (q == 0) sh_sc[row] = acc;
        }
    }
    __syncthreads();

    // tanh + bias pass (uniform, own-slot only), scorer out, ss partials
    if (t < DD) {
        float v = tanhf(sh_sc[t] + bmap[t]);
        sh_sc[t] = v;
        out2[(size_t)b * DD + t] = v;
        float ss = v * v;
        #pragma unroll
        for (int off = 32; off; off >>= 1) ss += __shfl_xor(ss, off, 64);
        if (lane == 0) redq[wave] = ss;
    }
    __syncthreads();

    // ================= Phase B: stream embs rows =================
    {
        const float4* scb = (const float4*)sh_sc;
        float4 S[16];
        #pragma unroll
        for (int k = 0; k < 16; ++k) S[k] = scb[q + 8 * k];

        const float* ebase = embs + (size_t)b * NN * DD;

        // blocks 0..49 of 8 rows; wave w handles w, w+16, w+32; waves 0,1 add 48,49
        #pragma unroll
        for (int j = 0; j < 3; ++j) {
            const int row = (j * 16 + wave) * 8 + rr;     // 0..383
            const float4* src = (const float4*)(ebase + (size_t)row * DD) + q;
            float a0 = 0.f, a1 = 0.f, a2 = 0.f, a3 = 0.f;
            #pragma unroll
            for (int k = 0; k < 16; ++k) {
                float4 e = src[8 * k];
                a0 += e.x * S[k].x;
                a1 += e.y * S[k].y;
                a2 += e.z * S[k].z;
                a3 += e.w * S[k].w;
            }
            float acc = (a0 + a1) + (a2 + a3);
            acc += __shfl_xor(acc, 1, 64);
            acc += __shfl_xor(acc, 2, 64);
            acc += __shfl_xor(acc, 4, 64);
            if (q == 0) sh_s[row] = acc;
        }
        if (wave < 2) {
            const int row = (48 + wave) * 8 + rr;         // 384..399
            const float4* src = (const float4*)(ebase + (size_t)row * DD) + q;
            float a0 = 0.f, a1 = 0.f, a2 = 0.f, a3 = 0.f;
            #pragma unroll
            for (int k = 0; k < 16; ++k) {
                float4 e = src[8 * k];
                a0 += e.x * S[k].x;
                a1 += e.y * S[k].y;
                a2 += e.z * S[k].z;
                a3 += e.w * S[k].w;
            }
            float acc = (a0 + a1) + (a2 + a3);
            acc += __shfl_xor(acc, 1, 64);
            acc += __shfl_xor(acc, 2, 64);
            acc += __shfl_xor(acc, 4, 64);
            if (q == 0) sh_s[row] = acc;
        }
    }
    __syncthreads();

    if (t == 0) {
        float tot = 0.f;
        #pragma unroll
        for (int i = 0; i < 8; ++i) tot += redq[i];
        mZ[0] = 1.0f / sqrtf(tot);
    }
    __syncthreads();
    const float inv = mZ[0];

    // ---- block max of scaled scores ----
    const float x = (t < NN) ? sh_s[t] * inv : -FLT_MAX;
    {
        float m = x;
        #pragma unroll
        for (int off = 32; off; off >>= 1) m = fmaxf(m, __shfl_xor(m, off, 64));
        if (lane == 0) redf[wave] = m;
    }
    __syncthreads();
    if (t == 0) {
        float m = redf[0];
        #pragma unroll
        for (int i = 1; i < 16; ++i) m = fmaxf(m, redf[i]);
        mZ[1] = m;
    }
    __syncthreads();
    const float m = mZ[1];

    // ---- Z and entropy sums ----
    {
        float e = 0.f, wv = 0.f;
        if (t < NN) {
            float d = x - m;
            e = expf(d);
            wv = e * d;
        }
        #pragma unroll
        for (int off = 32; off; off >>= 1) {
            e  += __shfl_xor(e, off, 64);
            wv += __shfl_xor(wv, off, 64);
        }
        if (lane == 0) { redf[wave] = e; redf2[wave] = wv; }
    }
    __syncthreads();
    if (t == 0) {
        float Z = 0.f, Ws = 0.f;
        #pragma unroll
        for (int i = 0; i < 16; ++i) { Z += redf[i]; Ws += redf2[i]; }
        float logZ = logf(Z);
        mZ[2] = logZ;
        out3[b] = logZ - Ws / Z;
    }
    __syncthreads();
    const float logZ = mZ[2];

    // ---- top-K on wave 0, fully in-register (r3-verified) ----
    if (wave == 0) {
        float v0 = sh_s[lane      ] * inv;
        float v1 = sh_s[lane +  64] * inv;
        float v2 = sh_s[lane + 128] * inv;
        float v3 = sh_s[lane + 192] * inv;
        float v4 = sh_s[lane + 256] * inv;
        float v5 = sh_s[lane + 320] * inv;
        float v6 = (lane + 384 < NN) ? sh_s[lane + 384] * inv : -FLT_MAX;
        float acc = 0.f;
        for (int k = 0; k < KK; ++k) {
            float bv = v0; int bi = lane;
            if (v1 > bv) { bv = v1; bi = lane + 64; }
            if (v2 > bv) { bv = v2; bi = lane + 128; }
            if (v3 > bv) { bv = v3; bi = lane + 192; }
            if (v4 > bv) { bv = v4; bi = lane + 256; }
            if (v5 > bv) { bv = v5; bi = lane + 320; }
            if (v6 > bv) { bv = v6; bi = lane + 384; }
            #pragma unroll
            for (int off = 32; off; off >>= 1) {
                float ov = __shfl_xor(bv, off, 64);
                int   oi = __shfl_xor(bi, off, 64);
                if (ov > bv || (ov == bv && oi < bi)) { bv = ov; bi = oi; }
            }
            if (lane == 0) {
                sh_topk[k] = bi;
                sh_th[k] = tanhf(bv);
                out4[(size_t)b * KK + k] = (float)bi;
                acc += bv - m - logZ;
            }
            v0 = (bi == lane      ) ? -FLT_MAX : v0;
            v1 = (bi == lane +  64) ? -FLT_MAX : v1;
            v2 = (bi == lane + 128) ? -FLT_MAX : v2;
            v3 = (bi == lane + 192) ? -FLT_MAX : v3;
            v4 = (bi == lane + 256) ? -FLT_MAX : v4;
            v5 = (bi == lane + 320) ? -FLT_MAX : v5;
            v6 = (bi == lane + 384) ? -FLT_MAX : v6;
        }
        if (lane == 0) out1[b] = acc / (float)KK;
    }
    __syncthreads();

    // ---- out0[b, j, k] = embs[b, topk[k], j] * th[k] ----
    if (t < NN) {
        int k = t / KK;
        int j = t - k * KK;
        float val = embs[((size_t)b * NN + sh_topk[k]) * DD + j] * sh_th[k];
        out0[(size_t)b * (KK * KK) + j * KK + k] = val;
    }
}

extern "C" void kernel_launch(void* const* d_in, const int* in_sizes, int n_in,
                              void* d_out, int out_size, void* d_ws, size_t ws_size,
                              hipStream_t stream) {
    const float* node_embs = (const float*)d_in[0];
    // d_in[1] = mask, unused
    const float* h_t   = (const float*)d_in[2];
    const float* W_map = (const float*)d_in[3];
    const float* b_map = (const float*)d_in[4];
    (void)in_sizes; (void)n_in; (void)out_size; (void)d_ws; (void)ws_size;

    float* ob = (float*)d_out;
    float* out0 = ob;                       // [B,K,K] -> 102400
    float* out1 = ob + 102400;              // [B]     -> 256
    float* out2 = ob + 102656;              // [B,D]   -> 131072
    float* out3 = ob + 233728;              // [B]     -> 256
    float* out4 = ob + 233984;              // [B,K]   -> 5120

    fused_topk_kernel<<<BB, 1024, 0, stream>>>(
        node_embs, h_t, W_map, b_map, out0, out1, out2, out3, out4);
}